// Round 3
// baseline (80.214 us; speedup 1.0000x reference)
//
#include <hip/hip_runtime.h>
#include <cstddef>

#define NB 64
#define NP 8732
#define NM 16
#define NC 21
#define S_SPLIT 16
#define PSPLIT 16
#define CH 546        // ceil(NP/PSPLIT)
#define TK_T 512
#define NK 18         // ceil(NP/TK_T)

// CLASS_W: base 1.0; [3,4,5,9,10,11,16,17,18]=2.5; [15,7,12,8]=0.75; [0]=0.5
__constant__ float c_w[NC] = {
    0.5f, 1.0f, 1.0f, 2.5f, 2.5f, 2.5f, 1.0f, 0.75f, 0.75f, 2.5f, 2.5f,
    2.5f, 0.75f, 1.0f, 1.0f, 0.75f, 2.5f, 2.5f, 2.5f, 1.0f, 1.0f};

// ------------- Kernel A: per-(batch, chunk) per-truth argmax partials -------------
__global__ __launch_bounds__(256) void k_argmax(
    const float4* __restrict__ defaults, const float4* __restrict__ gtb,
    float* __restrict__ pbv, int* __restrict__ pbi)
{
    const int b = blockIdx.x, s = blockIdx.y, t = threadIdx.x;
    __shared__ float s_t0[NM], s_t1[NM], s_t2[NM], s_t3[NM], s_area[NM];
    __shared__ float s_wv[NM][4];
    __shared__ int   s_wi[NM][4];

    if (t < NM) {
        float4 g = gtb[b * NM + t];
        s_t0[t] = g.x; s_t1[t] = g.y; s_t2[t] = g.z; s_t3[t] = g.w;
        s_area[t] = (g.z - g.x) * (g.w - g.y);
    }
    __syncthreads();

    float bpv[NM]; int bpi[NM];
    #pragma unroll
    for (int j = 0; j < NM; j++) { bpv[j] = -1.0f; bpi[j] = 0x7fffffff; }

    const int pend = min(NP, (s + 1) * CH);
    for (int p = s * CH + t; p < pend; p += 256) {
        float4 d = defaults[p];
        float a1 = (d.z - d.x) * (d.w - d.y);
        #pragma unroll
        for (int j = 0; j < NM; j++) {
            float w = fminf(d.z, s_t2[j]) - fmaxf(d.x, s_t0[j]);
            float h = fminf(d.w, s_t3[j]) - fmaxf(d.y, s_t1[j]);
            w = fmaxf(w, 0.0f); h = fmaxf(h, 0.0f);
            float inter = w * h;
            float iou = inter / (a1 + s_area[j] - inter);
            if (iou > bpv[j]) { bpv[j] = iou; bpi[j] = p; } // smallest p kept (ascending visit)
        }
    }

    const int lane = t & 63, wv = t >> 6;
    #pragma unroll
    for (int j = 0; j < NM; j++) {
        float v = bpv[j]; int i = bpi[j];
        #pragma unroll
        for (int off = 32; off > 0; off >>= 1) {
            float v2 = __shfl_down(v, off);
            int   i2 = __shfl_down(i, off);
            if (v2 > v || (v2 == v && i2 < i)) { v = v2; i = i2; }
        }
        if (lane == 0) { s_wv[j][wv] = v; s_wi[j][wv] = i; }
    }
    __syncthreads();
    if (t < NM) {
        float v = s_wv[t][0]; int i = s_wi[t][0];
        #pragma unroll
        for (int w = 1; w < 4; w++) {
            float v2 = s_wv[t][w]; int i2 = s_wi[t][w];
            if (v2 > v || (v2 == v && i2 < i)) { v = v2; i = i2; }
        }
        pbv[(b * PSPLIT + s) * NM + t] = v;
        pbi[(b * PSPLIT + s) * NM + t] = i;
    }
}

// ------- Kernel B: fused match-recompute + losses (LDS-staged conf) -------
__global__ __launch_bounds__(256) void k_loss(
    const float4* __restrict__ loc, const float* __restrict__ conf,
    const float* __restrict__ cent, const float4* __restrict__ defaults,
    const float4* __restrict__ gtb, const int* __restrict__ gtl,
    const float* __restrict__ pbv, const int* __restrict__ pbi,
    float* __restrict__ lossc,
    int* __restrict__ nposP, float* __restrict__ locP,
    float* __restrict__ centP, float* __restrict__ pfocP)
{
    const int b = blockIdx.x, s = blockIdx.y, t = threadIdx.x;
    __shared__ float s_t0[NM], s_t1[NM], s_t2[NM], s_t3[NM], s_area[NM];
    __shared__ int s_lab[NM], s_ovp[NM];
    __shared__ float s_conf[256 * NC];   // 21504 B

    if (t < NM) {
        float4 g = gtb[b * NM + t];
        s_t0[t] = g.x; s_t1[t] = g.y; s_t2[t] = g.z; s_t3[t] = g.w;
        s_area[t] = (g.z - g.x) * (g.w - g.y);
        s_lab[t] = gtl[b * NM + t];
        // combine per-chunk argmax partials -> global best prior for truth t
        float v = -2.0f; int i = 0x7fffffff;
        for (int c = 0; c < PSPLIT; c++) {
            float v2 = pbv[(b * PSPLIT + c) * NM + t];
            int   i2 = pbi[(b * PSPLIT + c) * NM + t];
            if (v2 > v || (v2 == v && i2 < i)) { v = v2; i = i2; }
        }
        s_ovp[t] = i;
    }
    __syncthreads();

    float locS = 0.0f, centS = 0.0f, pfocS = 0.0f; int np = 0;

    for (int it = 0; it < 3; it++) {
        const int base = s * 256 + it * 4096;
        if (base >= NP) break;
        const int size = min(256, NP - base);

        // stage conf window (contiguous, 16B-aligned) into LDS via float4
        const float4* csrc = (const float4*)(conf + ((size_t)b * NP + base) * NC);
        const int n_words = size * NC;
        const int n4 = n_words >> 2;
        for (int f = t; f < n4; f += 256)
            ((float4*)s_conf)[f] = csrc[f];
        if (t < (n_words & 3))
            s_conf[(n4 << 2) + t] = ((const float*)csrc)[(n4 << 2) + t];
        __syncthreads();

        if (t < size) {
            const int p = base + t;
            float4 d = defaults[p];
            float a1 = (d.z - d.x) * (d.w - d.y);
            float bv = -1.0f; int bj = 0;
            #pragma unroll
            for (int j = 0; j < NM; j++) {
                float w = fminf(d.z, s_t2[j]) - fmaxf(d.x, s_t0[j]);
                float h = fminf(d.w, s_t3[j]) - fmaxf(d.y, s_t1[j]);
                w = fmaxf(w, 0.0f); h = fmaxf(h, 0.0f);
                float inter = w * h;
                float iou = inter / (a1 + s_area[j] - inter);
                if (iou > bv) { bv = iou; bj = j; }   // first-occurrence over j
            }
            // sequential override semantics: later j wins -> scan j high->low
            #pragma unroll
            for (int j = NM - 1; j >= 0; j--) {
                if (s_ovp[j] == p) { bj = j; bv = 2.0f; break; }
            }
            int lab = (bv < 0.5f) ? 0 : s_lab[bj];
            bool pos = lab > 0;

            const float* cp = s_conf + t * NC;
            float m = cp[0];
            #pragma unroll
            for (int c = 1; c < NC; c++) m = fmaxf(m, cp[c]);
            float se = 0.0f;
            #pragma unroll
            for (int c = 0; c < NC; c++) se += __expf(cp[c] - m);
            float logpt = cp[lab] - m - __logf(se);
            float ce = -logpt;
            float pt = __expf(logpt);
            float omp = 1.0f - pt;
            float focal = 0.25f * omp * omp * c_w[lab] * ce;

            lossc[b * NP + p] = pos ? 0.0f : focal;

            if (pos) {
                float g0 = s_t0[bj], g1 = s_t1[bj], g2 = s_t2[bj], g3 = s_t3[bj];
                float dw = d.z - d.x, dh = d.w - d.y;
                float gw = g2 - g0,  gh = g3 - g1;
                float dcx = d.x + dw * 0.5f, dcy = d.y + dh * 0.5f;
                float gcx = g0 + gw * 0.5f,  gcy = g1 + gh * 0.5f;
                float e0 = (gcx - dcx) / (dw * 0.1f + 1e-8f);
                float e1 = (gcy - dcy) / (dh * 0.1f + 1e-8f);
                float e2 = logf(gw / (dw + 1e-8f) + 1e-8f) / 0.1f;
                float e3 = logf(gh / (dh + 1e-8f) + 1e-8f) / 0.1f;
                float4 lp = loc[(size_t)b * NP + p];
                float a, sl = 0.0f;
                a = fabsf(lp.x - e0); sl += (a < 1.0f) ? 0.5f * a * a : a - 0.5f;
                a = fabsf(lp.y - e1); sl += (a < 1.0f) ? 0.5f * a * a : a - 0.5f;
                a = fabsf(lp.z - e2); sl += (a < 1.0f) ? 0.5f * a * a : a - 0.5f;
                a = fabsf(lp.w - e3); sl += (a < 1.0f) ? 0.5f * a * a : a - 0.5f;
                locS += sl;

                float ccx = (g0 + g2) * 0.5f, ccy = (g1 + g3) * 0.5f;
                float ld = ccx - g0, rd = g2 - ccx, td = ccy - g1, bd = g3 - ccy;
                float centT = sqrtf((fminf(ld, rd) / fmaxf(ld, rd + 1e-8f)) *
                                    (fminf(td, bd) / fmaxf(td, bd + 1e-8f)));
                float x = cent[(size_t)b * NP + p];
                float bce = fmaxf(x, 0.0f) - x * centT + log1pf(expf(-fabsf(x)));
                centS += bce;
                pfocS += focal;
                np++;
            }
        }
        __syncthreads();   // protect s_conf before next window overwrite
    }

    const int lane = t & 63, wv = t >> 6;
    float fnp = (float)np;
    #pragma unroll
    for (int off = 32; off > 0; off >>= 1) {
        locS  += __shfl_down(locS,  off);
        centS += __shfl_down(centS, off);
        pfocS += __shfl_down(pfocS, off);
        fnp   += __shfl_down(fnp,   off);
    }
    __shared__ float r0[4], r1[4], r2[4], r3[4];
    if (lane == 0) { r0[wv] = locS; r1[wv] = centS; r2[wv] = pfocS; r3[wv] = fnp; }
    __syncthreads();
    if (t == 0) {
        int idx = b * S_SPLIT + s;
        locP[idx]  = r0[0] + r0[1] + r0[2] + r0[3];
        centP[idx] = r1[0] + r1[1] + r1[2] + r1[3];
        pfocP[idx] = r2[0] + r2[1] + r2[2] + r2[3];
        nposP[idx] = (int)(r3[0] + r3[1] + r3[2] + r3[3]);
    }
}

// ------- Kernel C: per-batch top-k sum (register keys, 2-bit radix search) -------
__global__ __launch_bounds__(TK_T) void k_topk(
    const float* __restrict__ lossc, const int* __restrict__ nposP,
    float* __restrict__ topkP, float* __restrict__ selcP)
{
    const int b = blockIdx.x, t = threadIdx.x;
    const int lane = t & 63, wv = t >> 6;
    __shared__ int s_c[3][8];
    __shared__ float s_f[8];

    unsigned ukey[NK];
    #pragma unroll
    for (int i = 0; i < NK; i++) {
        int p = i * TK_T + t;
        ukey[i] = (p < NP) ? __float_as_uint(lossc[b * NP + p]) : 0u;
    }

    int np = 0;
    for (int s = 0; s < S_SPLIT; s++) np += nposP[b * S_SPLIT + s];
    const int k = min(3 * np, NP - 1);

    unsigned vk = 0;
    if (k > 0) {
        for (int sh = 30; sh >= 0; sh -= 2) {
            int c1 = 0, c2 = 0, c3 = 0;
            const unsigned t1 = vk | (1u << sh), t2 = vk | (2u << sh), t3 = vk | (3u << sh);
            #pragma unroll
            for (int i = 0; i < NK; i++) {
                unsigned kk = ukey[i];
                c1 += (kk >= t1); c2 += (kk >= t2); c3 += (kk >= t3);
            }
            #pragma unroll
            for (int off = 32; off > 0; off >>= 1) {
                c1 += __shfl_down(c1, off);
                c2 += __shfl_down(c2, off);
                c3 += __shfl_down(c3, off);
            }
            if (lane == 0) { s_c[0][wv] = c1; s_c[1][wv] = c2; s_c[2][wv] = c3; }
            __syncthreads();
            int T1 = 0, T2 = 0, T3 = 0;
            #pragma unroll
            for (int w = 0; w < 8; w++) { T1 += s_c[0][w]; T2 += s_c[1][w]; T3 += s_c[2][w]; }
            __syncthreads();
            if      (T3 >= k) vk = t3;
            else if (T2 >= k) vk = t2;
            else if (T1 >= k) vk = t1;
        }
    }

    int cgt = 0; float sgt = 0.0f;
    #pragma unroll
    for (int i = 0; i < NK; i++) {
        unsigned kk = ukey[i];
        if (kk > vk) { cgt++; sgt += __uint_as_float(kk); }
    }
    #pragma unroll
    for (int off = 32; off > 0; off >>= 1) {
        cgt += __shfl_down(cgt, off);
        sgt += __shfl_down(sgt, off);
    }
    if (lane == 0) { s_c[0][wv] = cgt; s_f[wv] = sgt; }
    __syncthreads();
    if (t == 0) {
        int tc = 0; float ts = 0.0f;
        #pragma unroll
        for (int w = 0; w < 8; w++) { tc += s_c[0][w]; ts += s_f[w]; }
        float topk = (k > 0) ? (ts + (float)(k - tc) * __uint_as_float(vk)) : 0.0f;
        topkP[b] = topk;
        selcP[b] = (float)(np + k);
    }
}

// ---------------- Kernel D: final combine ----------------
__global__ __launch_bounds__(256) void k_final(
    const int* __restrict__ nposP, const float* __restrict__ locP,
    const float* __restrict__ centP, const float* __restrict__ pfocP,
    const float* __restrict__ topkP, const float* __restrict__ selcP,
    float* __restrict__ out)
{
    const int t = threadIdx.x;
    const int lane = t & 63, wv = t >> 6;
    float l = 0.0f, c = 0.0f, pf = 0.0f, np = 0.0f, tk = 0.0f, sc = 0.0f;
    for (int i = t; i < NB * S_SPLIT; i += 256) {
        np += (float)nposP[i]; l += locP[i]; c += centP[i]; pf += pfocP[i];
    }
    if (t < NB) { tk = topkP[t]; sc = selcP[t]; }

    #pragma unroll
    for (int off = 32; off > 0; off >>= 1) {
        l  += __shfl_down(l,  off);
        c  += __shfl_down(c,  off);
        pf += __shfl_down(pf, off);
        np += __shfl_down(np, off);
        tk += __shfl_down(tk, off);
        sc += __shfl_down(sc, off);
    }
    __shared__ float s6[6][4];
    if (lane == 0) {
        s6[0][wv] = l; s6[1][wv] = c; s6[2][wv] = pf;
        s6[3][wv] = np; s6[4][wv] = tk; s6[5][wv] = sc;
    }
    __syncthreads();
    if (t == 0) {
        float L  = s6[0][0] + s6[0][1] + s6[0][2] + s6[0][3];
        float C  = s6[1][0] + s6[1][1] + s6[1][2] + s6[1][3];
        float PF = s6[2][0] + s6[2][1] + s6[2][2] + s6[2][3];
        float NPs= s6[3][0] + s6[3][1] + s6[3][2] + s6[3][3];
        float TK = s6[4][0] + s6[4][1] + s6[4][2] + s6[4][3];
        float SC = s6[5][0] + s6[5][1] + s6[5][2] + s6[5][3];
        out[0] = 2.0f * (L / NPs) + (PF + TK) / SC + (C / NPs);
    }
}

extern "C" void kernel_launch(void* const* d_in, const int* in_sizes, int n_in,
                              void* d_out, int out_size, void* d_ws, size_t ws_size,
                              hipStream_t stream) {
    const float4* loc      = (const float4*)d_in[0];
    const float*  conf     = (const float*)d_in[1];
    const float*  cent     = (const float*)d_in[2];
    const float4* defaults = (const float4*)d_in[3];
    const float4* gtb      = (const float4*)d_in[4];
    const int*    gtl      = (const int*)d_in[5];
    float* out = (float*)d_out;

    const size_t BP = (size_t)NB * NP;
    char* w = (char*)d_ws;
    float* lossc = (float*)w;                                  // BP
    char* w2 = w + BP * 4;
    int*   nposP = (int*)w2;                                   // NB*S_SPLIT
    float* locP  = (float*)(w2 + 1 * NB * S_SPLIT * 4);
    float* centP = (float*)(w2 + 2 * NB * S_SPLIT * 4);
    float* pfocP = (float*)(w2 + 3 * NB * S_SPLIT * 4);
    float* topkP = (float*)(w2 + 4 * NB * S_SPLIT * 4);        // NB
    float* selcP = (float*)(w2 + 4 * NB * S_SPLIT * 4 + NB * 4);
    char* w3 = w2 + 4 * NB * S_SPLIT * 4 + 2 * NB * 4;
    float* pbv = (float*)w3;                                   // NB*PSPLIT*NM
    int*   pbi = (int*)(w3 + NB * PSPLIT * NM * 4);

    k_argmax<<<dim3(NB, PSPLIT), 256, 0, stream>>>(defaults, gtb, pbv, pbi);
    k_loss<<<dim3(NB, S_SPLIT), 256, 0, stream>>>(loc, conf, cent, defaults, gtb, gtl,
                                                  pbv, pbi, lossc, nposP, locP, centP, pfocP);
    k_topk<<<NB, TK_T, 0, stream>>>(lossc, nposP, topkP, selcP);
    k_final<<<1, 256, 0, stream>>>(nposP, locP, centP, pfocP, topkP, selcP, out);
}